// Round 2
// baseline (790.567 us; speedup 1.0000x reference)
//
#include <hip/hip_runtime.h>
#include <math.h>

constexpr int B = 1024, C = 256, DF = 512, DT = 512, HID = 32;

// ---------------- Kernel 1: qtil[b,f] = sum_t Q[b,t] * Wk_w[t,f]  (fp32) ----------------
// Round-1 finding: the 2 GiB workspace poison fills run unconditionally per timed
// iteration (~660 us fixed floor), so using d_ws is free. qtil + r live in d_ws.
__global__ __launch_bounds__(256) void qproj_kernel(const float* __restrict__ Q,
                                                    const float* __restrict__ Wk,
                                                    float* __restrict__ qtil) {
    __shared__ __align__(16) float qs[4][DT];
    const int tid = threadIdx.x;
    const int b0 = blockIdx.x * 4;
#pragma unroll
    for (int bb = 0; bb < 4; bb++) {
        qs[bb][tid]       = Q[(b0 + bb) * DT + tid];
        qs[bb][tid + 256] = Q[(b0 + bb) * DT + tid + 256];
    }
    __syncthreads();
    const int f0 = tid * 2;
    float acc0[4] = {0.f, 0.f, 0.f, 0.f};
    float acc1[4] = {0.f, 0.f, 0.f, 0.f};
    for (int t4 = 0; t4 < DT; t4 += 4) {
        float q[4][4];
#pragma unroll
        for (int bb = 0; bb < 4; bb++) {
            float4 qv = *(const float4*)&qs[bb][t4];
            q[bb][0] = qv.x; q[bb][1] = qv.y; q[bb][2] = qv.z; q[bb][3] = qv.w;
        }
#pragma unroll
        for (int k = 0; k < 4; k++) {
            float2 w = *(const float2*)(Wk + (size_t)(t4 + k) * DF + f0);
#pragma unroll
            for (int bb = 0; bb < 4; bb++) {
                acc0[bb] += q[bb][k] * w.x;
                acc1[bb] += q[bb][k] * w.y;
            }
        }
    }
#pragma unroll
    for (int bb = 0; bb < 4; bb++) {
        float2 o; o.x = acc0[bb]; o.y = acc1[bb];
        *(float2*)(qtil + (size_t)(b0 + bb) * DF + f0) = o;
    }
}

// ---------------- Kernel 2: one block per batch ----------------
// Streaming softmax/abs pass + gate MLP. Writes r[b] (normalized weighted feature
// sum, feature space) to global and gate to out1. The Wv projection moved to
// vproj_kernel: doing it here forced every one of 1024 blocks to stream the full
// 1 MB Wv => 1 GB L2 traffic (~30 us). vproj amortizes Wv over 4 batches/block.
__global__ __launch_bounds__(256) void main_kernel(
    const float* __restrict__ Q, const float* __restrict__ feat,
    const float* __restrict__ qtil,
    const float* __restrict__ g1w, const float* __restrict__ g1b,
    const float* __restrict__ g2w, const float* __restrict__ g2b,
    float* __restrict__ rg, float* __restrict__ out1) {

    __shared__ __align__(16) float s_q[DF];       // qtil[b]
    __shared__ __align__(16) float s_Q[DT];       // Q[b] (gate MLP)
    __shared__ __align__(16) float s_part[4][DF]; // per-wave partial r
    __shared__ float s_m[4], s_l[4], s_abs[4];
    __shared__ float s_hp[HID][8];
    __shared__ float s_h[HID];

    const int tid  = threadIdx.x;
    const int lane = tid & 63;
    const int wv   = tid >> 6;   // 4 waves
    const int b    = blockIdx.x;

    s_q[tid]       = qtil[b * DF + tid];
    s_q[tid + 256] = qtil[b * DF + tid + 256];
    s_Q[tid]       = Q[b * DT + tid];
    s_Q[tid + 256] = Q[b * DT + tid + 256];
    __syncthreads();

    float qreg[8];
    {
        float4 a0 = *(const float4*)&s_q[lane * 8];
        float4 a1 = *(const float4*)&s_q[lane * 8 + 4];
        qreg[0] = a0.x; qreg[1] = a0.y; qreg[2] = a0.z; qreg[3] = a0.w;
        qreg[4] = a1.x; qreg[5] = a1.y; qreg[6] = a1.z; qreg[7] = a1.w;
    }

    const float* fb = feat + (size_t)b * C * DF;
    float r[8] = {0.f, 0.f, 0.f, 0.f, 0.f, 0.f, 0.f, 0.f};
    float m = -INFINITY, l = 0.f, sabs = 0.f;
    const float rs = 0.044194173824159216f;  // 1/sqrt(512)

    // streaming pass: scores + online softmax + weighted feature sum + abs-sum
    for (int c = wv * 64; c < wv * 64 + 64; c += 2) {
        const float* row0 = fb + (size_t)c * DF + lane * 8;
        const float* row1 = row0 + DF;
        float4 x0a = *(const float4*)row0;
        float4 x0b = *(const float4*)(row0 + 4);
        float4 x1a = *(const float4*)row1;
        float4 x1b = *(const float4*)(row1 + 4);
        float v0[8] = {x0a.x, x0a.y, x0a.z, x0a.w, x0b.x, x0b.y, x0b.z, x0b.w};
        float v1[8] = {x1a.x, x1a.y, x1a.z, x1a.w, x1b.x, x1b.y, x1b.z, x1b.w};
        float dot0 = 0.f, dot1 = 0.f;
#pragma unroll
        for (int j = 0; j < 8; j++) {
            dot0 += v0[j] * qreg[j];
            dot1 += v1[j] * qreg[j];
            sabs += fabsf(v0[j]) + fabsf(v1[j]);
        }
#pragma unroll
        for (int off = 1; off < 64; off <<= 1) {
            dot0 += __shfl_xor(dot0, off, 64);
            dot1 += __shfl_xor(dot1, off, 64);
        }
        float s0 = dot0 * rs, s1 = dot1 * rs;
        float m2 = fmaxf(fmaxf(m, s0), s1);
        float a  = __expf(m - m2);
        float p0 = __expf(s0 - m2);
        float p1 = __expf(s1 - m2);
        l = l * a + p0 + p1;
#pragma unroll
        for (int j = 0; j < 8; j++) r[j] = r[j] * a + p0 * v0[j] + p1 * v1[j];
        m = m2;
    }
#pragma unroll
    for (int off = 1; off < 64; off <<= 1) sabs += __shfl_xor(sabs, off, 64);
    if (lane == 0) { s_m[wv] = m; s_l[wv] = l; s_abs[wv] = sabs; }
    __syncthreads();

    float M = fmaxf(fmaxf(s_m[0], s_m[1]), fmaxf(s_m[2], s_m[3]));
    float L = s_l[0] * __expf(s_m[0] - M) + s_l[1] * __expf(s_m[1] - M) +
              s_l[2] * __expf(s_m[2] - M) + s_l[3] * __expf(s_m[3] - M);
    float msc = __expf(m - M);
#pragma unroll
    for (int j = 0; j < 8; j++) s_part[wv][lane * 8 + j] = r[j] * msc;
    float fscale = (s_abs[0] + s_abs[1] + s_abs[2] + s_abs[3]) * (1.0f / (float)(C * DF));
    __syncthreads();

    float invL = 1.0f / L;
#pragma unroll
    for (int k = 0; k < 2; k++) {
        int f = tid + 256 * k;
        float val = (s_part[0][f] + s_part[1][f] + s_part[2][f] + s_part[3][f]) * invL;
        rg[(size_t)b * DF + f] = val;  // coalesced
    }

    // gate MLP partials: 8 threads per hidden unit
    {
        int i = tid >> 3, g = tid & 7;
        const float* row = g1w + (size_t)i * (DT + 1);
        float part = 0.f;
        for (int t = g * 64; t < g * 64 + 64; ++t) part += row[t] * s_Q[t];
        if (g == 0) part += row[DT] * fscale;
        s_hp[i][g] = part;
    }
    __syncthreads();
    if (tid < HID) {
        float x = g1b[tid];
#pragma unroll
        for (int g = 0; g < 8; ++g) x += s_hp[tid][g];
        s_h[tid] = 0.5f * x * (1.0f + erff(x * 0.70710678118654752f));  // exact gelu
    }
    __syncthreads();
    if (tid == 0) {
        float z = g2b[0];
        for (int i = 0; i < HID; ++i) z += s_h[i] * g2w[i];
        out1[b] = 1.0f / (1.0f + __expf(-z));
    }
}

// ---------------- Kernel 3: out0[b,t] = gate[b] * (sum_f r[b,f]*Wv[t,f] + Wvb[t]) ------
// 4 batches per block, 256 blocks (1/CU), 512 threads (8 waves, 2/SIMD for L2
// latency hiding). Wv streamed once per block: 256 MB L2 traffic vs 1 GB before.
__global__ __launch_bounds__(512) void vproj_kernel(
    const float* __restrict__ rg, const float* __restrict__ gates,
    const float* __restrict__ Wv, const float* __restrict__ Wvb,
    float* __restrict__ out0) {

    __shared__ __align__(16) float s_r4[4][DF];   // r rows b0..b0+3
    __shared__ __align__(16) float s_o[4][DT];    // output staging

    const int tid  = threadIdx.x;
    const int lane = tid & 63;
    const int wv   = tid >> 6;          // 8 waves
    const int b0   = blockIdx.x * 4;

    // rows b0..b0+3 of rg are contiguous: flat coalesced stage of 4*512 floats
    {
        const float* src = rg + (size_t)b0 * DF;
        float* dst = &s_r4[0][0];
#pragma unroll
        for (int k = 0; k < 4; k++) dst[tid + 512 * k] = src[tid + 512 * k];
    }
    __syncthreads();

    float rr[4][8];
#pragma unroll
    for (int bb = 0; bb < 4; bb++) {
        float4 a0 = *(const float4*)&s_r4[bb][lane * 8];
        float4 a1 = *(const float4*)&s_r4[bb][lane * 8 + 4];
        rr[bb][0] = a0.x; rr[bb][1] = a0.y; rr[bb][2] = a0.z; rr[bb][3] = a0.w;
        rr[bb][4] = a1.x; rr[bb][5] = a1.y; rr[bb][6] = a1.z; rr[bb][7] = a1.w;
    }
    float g4[4];
#pragma unroll
    for (int bb = 0; bb < 4; bb++) g4[bb] = gates[b0 + bb];

    // each wave owns 64 t-rows; 2 rows per iteration
    for (int t = wv * 64; t < wv * 64 + 64; t += 2) {
        const float* w0p = Wv + (size_t)t * DF + lane * 8;
        const float* w1p = w0p + DF;
        float4 w0a = *(const float4*)w0p;
        float4 w0b = *(const float4*)(w0p + 4);
        float4 w1a = *(const float4*)w1p;
        float4 w1b = *(const float4*)(w1p + 4);
        float w0[8] = {w0a.x, w0a.y, w0a.z, w0a.w, w0b.x, w0b.y, w0b.z, w0b.w};
        float w1[8] = {w1a.x, w1a.y, w1a.z, w1a.w, w1b.x, w1b.y, w1b.z, w1b.w};
        float d0[4], d1[4];
#pragma unroll
        for (int bb = 0; bb < 4; bb++) {
            float a = 0.f, c = 0.f;
#pragma unroll
            for (int j = 0; j < 8; j++) {
                a += w0[j] * rr[bb][j];
                c += w1[j] * rr[bb][j];
            }
            d0[bb] = a; d1[bb] = c;
        }
#pragma unroll
        for (int off = 1; off < 64; off <<= 1) {
#pragma unroll
            for (int bb = 0; bb < 4; bb++) {
                d0[bb] += __shfl_xor(d0[bb], off, 64);
                d1[bb] += __shfl_xor(d1[bb], off, 64);
            }
        }
        if (lane == 0) {
            float vb0 = Wvb[t], vb1 = Wvb[t + 1];
#pragma unroll
            for (int bb = 0; bb < 4; bb++) {
                s_o[bb][t]     = g4[bb] * (d0[bb] + vb0);
                s_o[bb][t + 1] = g4[bb] * (d1[bb] + vb1);
            }
        }
    }
    __syncthreads();
    // s_o flat layout == out0 rows b0..b0+3: one coalesced float4 per thread
    *(float4*)(out0 + (size_t)b0 * DT + 4 * tid) = *(const float4*)(&s_o[0][0] + 4 * tid);
}

extern "C" void kernel_launch(void* const* d_in, const int* in_sizes, int n_in,
                              void* d_out, int out_size, void* d_ws, size_t ws_size,
                              hipStream_t stream) {
    const float* Q    = (const float*)d_in[0];
    const float* feat = (const float*)d_in[1];
    const float* Wk   = (const float*)d_in[2];
    // d_in[3] = Wk_b: constant across channels -> cancels in softmax (zeros), unused.
    const float* Wv   = (const float*)d_in[4];
    const float* Wvb  = (const float*)d_in[5];
    const float* g1w  = (const float*)d_in[6];
    const float* g1b  = (const float*)d_in[7];
    const float* g2w  = (const float*)d_in[8];
    const float* g2b  = (const float*)d_in[9];
    float* out0 = (float*)d_out;
    float* out1 = out0 + (size_t)B * DT;
    float* qtil = (float*)d_ws;                 // 2 MB
    float* rg   = (float*)d_ws + (size_t)B * DF; // 2 MB

    hipLaunchKernelGGL(qproj_kernel, dim3(B / 4), dim3(256), 0, stream, Q, Wk, qtil);
    hipLaunchKernelGGL(main_kernel, dim3(B), dim3(256), 0, stream,
                       Q, feat, qtil, g1w, g1b, g2w, g2b, rg, out1);
    hipLaunchKernelGGL(vproj_kernel, dim3(B / 4), dim3(512), 0, stream,
                       rg, out1, Wv, Wvb, out0);
}

// Round 3
// 767.585 us; speedup vs baseline: 1.0299x; 1.0299x over previous
//
#include <hip/hip_runtime.h>
#include <math.h>

constexpr int B = 1024, C = 256, DF = 512, DT = 512, HID = 32;
constexpr int BB = 4;     // batches per block
// grid = B/BB = 256 blocks = exactly 1 per CU; 1024 threads = 16 waves/CU.

// Single fused kernel. Rationale (rounds 0-2 evidence): the harness's two 2-GiB
// workspace poison fills (~660 us @80% HBM) are an unconditional per-iteration
// floor; our controllable slice is ~130 us of which ~80 us is the HBM floor for
// streaming `features` once. The rest was kernel-boundary drains + scratch
// round-trips, eliminated here by fusing qproj + streaming-softmax + gate MLP +
// Wv projection into one launch with 4 batches/block so Wk/Wv L2 traffic stays
// at 256 MB each (~7 us apiece).
__global__ __launch_bounds__(1024) void fused_kernel(
    const float* __restrict__ Q, const float* __restrict__ feat,
    const float* __restrict__ Wk,
    const float* __restrict__ Wv, const float* __restrict__ Wvb,
    const float* __restrict__ g1w, const float* __restrict__ g1b,
    const float* __restrict__ g2w, const float* __restrict__ g2b,
    float* __restrict__ out0, float* __restrict__ out1) {

    __shared__ __align__(16) float s_Q[BB][DT];     // Q rows: qproj + gate MLP
    __shared__ __align__(16) float s_qt[BB][DF];    // qtil; reused as s_r after streaming
    __shared__ __align__(16) float s_part[16][DF];  // per-wave partial r; reused as s_o
    __shared__ float s_m[16], s_l[16], s_abs[16];
    __shared__ float s_hp[BB][HID][8];
    __shared__ float s_h[BB][HID];
    __shared__ float s_gate[BB];

    const int tid  = threadIdx.x;
    const int lane = tid & 63;
    const int wv   = tid >> 6;          // 0..15
    const int bb_w = wv >> 2;           // this wave's batch (phases 1)
    const int b0   = blockIdx.x * BB;

    // ---- stage Q rows b0..b0+3 (contiguous 2048 floats) ----
    {
        float* dst = &s_Q[0][0];
        dst[tid]        = Q[(size_t)b0 * DT + tid];
        dst[tid + 1024] = Q[(size_t)b0 * DT + tid + 1024];
    }
    __syncthreads();

    // ---- phase 0: qtil[bb][f] = sum_t Q[bb][t] * Wk[t][f] (2 batches/thread) ----
    {
        const int f  = tid & 511;
        const int bq = tid >> 9;        // 0..1 -> batches bq and bq+2
        float acc0 = 0.f, acc1 = 0.f;
        for (int t = 0; t < DT; t += 4) {
#pragma unroll
            for (int k = 0; k < 4; k++) {
                float w = Wk[(size_t)(t + k) * DF + f];   // coalesced row read
                acc0 += s_Q[bq][t + k] * w;                // LDS broadcast
                acc1 += s_Q[bq + 2][t + k] * w;
            }
        }
        s_qt[bq][f]     = acc0;
        s_qt[bq + 2][f] = acc1;
    }
    __syncthreads();

    float qreg[8];
    {
        float4 a0 = *(const float4*)&s_qt[bb_w][lane * 8];
        float4 a1 = *(const float4*)&s_qt[bb_w][lane * 8 + 4];
        qreg[0] = a0.x; qreg[1] = a0.y; qreg[2] = a0.z; qreg[3] = a0.w;
        qreg[4] = a1.x; qreg[5] = a1.y; qreg[6] = a1.z; qreg[7] = a1.w;
    }
    // (no extra sync needed: the post-streaming sync orders qreg loads before
    //  s_qt is overwritten as s_r)

    // ---- phase 1: streaming scores + online softmax + weighted sum + abs-sum ----
    const float* fb = feat + (size_t)(b0 + bb_w) * C * DF;
    float r[8] = {0.f, 0.f, 0.f, 0.f, 0.f, 0.f, 0.f, 0.f};
    float m = -INFINITY, l = 0.f, sabs = 0.f;
    const float rs = 0.044194173824159216f;  // 1/sqrt(512)

    const int c0 = (wv & 3) * 64;
    for (int c = c0; c < c0 + 64; c += 2) {
        const float* row0 = fb + (size_t)c * DF + lane * 8;
        const float* row1 = row0 + DF;
        float4 x0a = *(const float4*)row0;
        float4 x0b = *(const float4*)(row0 + 4);
        float4 x1a = *(const float4*)row1;
        float4 x1b = *(const float4*)(row1 + 4);
        float v0[8] = {x0a.x, x0a.y, x0a.z, x0a.w, x0b.x, x0b.y, x0b.z, x0b.w};
        float v1[8] = {x1a.x, x1a.y, x1a.z, x1a.w, x1b.x, x1b.y, x1b.z, x1b.w};
        float dot0 = 0.f, dot1 = 0.f;
#pragma unroll
        for (int j = 0; j < 8; j++) {
            dot0 += v0[j] * qreg[j];
            dot1 += v1[j] * qreg[j];
            sabs += fabsf(v0[j]) + fabsf(v1[j]);
        }
#pragma unroll
        for (int off = 1; off < 64; off <<= 1) {
            dot0 += __shfl_xor(dot0, off, 64);
            dot1 += __shfl_xor(dot1, off, 64);
        }
        float s0 = dot0 * rs, s1 = dot1 * rs;
        float m2 = fmaxf(fmaxf(m, s0), s1);
        float a  = __expf(m - m2);
        float p0 = __expf(s0 - m2);
        float p1 = __expf(s1 - m2);
        l = l * a + p0 + p1;
#pragma unroll
        for (int j = 0; j < 8; j++) r[j] = r[j] * a + p0 * v0[j] + p1 * v1[j];
        m = m2;
    }
#pragma unroll
    for (int off = 1; off < 64; off <<= 1) sabs += __shfl_xor(sabs, off, 64);
    if (lane == 0) { s_m[wv] = m; s_l[wv] = l; s_abs[wv] = sabs; }
    __syncthreads();

    // rescale per-wave partials to the batch max, deposit to LDS
    {
        const int w0 = bb_w * 4;
        float M = fmaxf(fmaxf(s_m[w0], s_m[w0 + 1]), fmaxf(s_m[w0 + 2], s_m[w0 + 3]));
        float msc = __expf(m - M);
#pragma unroll
        for (int j = 0; j < 8; j++) s_part[wv][lane * 8 + j] = r[j] * msc;
    }
    __syncthreads();

    // ---- combine: s_r[bb][f] (overlays s_qt) ----
    float* s_r = &s_qt[0][0];
    {
        const int f  = tid & 511;
        const int bq = tid >> 9;   // batches bq, bq+2
#pragma unroll
        for (int h = 0; h < 2; h++) {
            const int bb = bq + 2 * h;
            const int w0 = bb * 4;
            float M = fmaxf(fmaxf(s_m[w0], s_m[w0 + 1]), fmaxf(s_m[w0 + 2], s_m[w0 + 3]));
            float L = s_l[w0]     * __expf(s_m[w0]     - M)
                    + s_l[w0 + 1] * __expf(s_m[w0 + 1] - M)
                    + s_l[w0 + 2] * __expf(s_m[w0 + 2] - M)
                    + s_l[w0 + 3] * __expf(s_m[w0 + 3] - M);
            float val = (s_part[w0][f] + s_part[w0 + 1][f] +
                         s_part[w0 + 2][f] + s_part[w0 + 3][f]) / L;
            s_r[bb * DF + f] = val;
        }
    }

    // ---- phase 2: gate MLP, 4 batches in parallel (256 threads each) ----
    {
        const int bg = tid >> 8;           // 0..3
        const int i  = (tid >> 3) & 31;    // hidden unit
        const int g  = tid & 7;            // 8-way split over DT
        const float* row = g1w + (size_t)i * (DT + 1);
        float part = 0.f;
        for (int t = g * 64; t < g * 64 + 64; ++t) part += row[t] * s_Q[bg][t];
        if (g == 0) {
            const int w0 = bg * 4;
            float fscale = (s_abs[w0] + s_abs[w0 + 1] + s_abs[w0 + 2] + s_abs[w0 + 3])
                           * (1.0f / (float)(C * DF));
            part += row[DT] * fscale;
        }
        s_hp[bg][i][g] = part;
    }
    __syncthreads();
    if (tid < BB * HID) {
        const int bh = tid >> 5, i = tid & 31;
        float x = g1b[i];
#pragma unroll
        for (int g = 0; g < 8; ++g) x += s_hp[bh][i][g];
        s_h[bh][i] = 0.5f * x * (1.0f + erff(x * 0.70710678118654752f));  // exact gelu
    }
    __syncthreads();
    if (tid < BB) {
        float z = g2b[0];
        for (int i = 0; i < HID; ++i) z += s_h[tid][i] * g2w[i];
        float gate = 1.0f / (1.0f + __expf(-z));
        s_gate[tid] = gate;
        out1[b0 + tid] = gate;
    }
    __syncthreads();

    // ---- phase 3: out0[bb,t] = gate * (Wv[t,:] . r[bb] + Wvb[t]) ----
    float* s_o = &s_part[0][0];   // overlays s_part (dead after combine)
    float rr[BB][8];
#pragma unroll
    for (int bb = 0; bb < BB; bb++) {
        float4 a0 = *(const float4*)&s_r[bb * DF + lane * 8];
        float4 a1 = *(const float4*)&s_r[bb * DF + lane * 8 + 4];
        rr[bb][0] = a0.x; rr[bb][1] = a0.y; rr[bb][2] = a0.z; rr[bb][3] = a0.w;
        rr[bb][4] = a1.x; rr[bb][5] = a1.y; rr[bb][6] = a1.z; rr[bb][7] = a1.w;
    }
    float g4[BB];
#pragma unroll
    for (int bb = 0; bb < BB; bb++) g4[bb] = s_gate[bb];

    for (int t = wv * 32; t < wv * 32 + 32; t += 2) {   // 32 t-rows per wave
        const float* w0p = Wv + (size_t)t * DF + lane * 8;
        const float* w1p = w0p + DF;
        float4 w0a = *(const float4*)w0p;
        float4 w0b = *(const float4*)(w0p + 4);
        float4 w1a = *(const float4*)w1p;
        float4 w1b = *(const float4*)(w1p + 4);
        float w0[8] = {w0a.x, w0a.y, w0a.z, w0a.w, w0b.x, w0b.y, w0b.z, w0b.w};
        float w1[8] = {w1a.x, w1a.y, w1a.z, w1a.w, w1b.x, w1b.y, w1b.z, w1b.w};
        float d0[BB], d1[BB];
#pragma unroll
        for (int bb = 0; bb < BB; bb++) {
            float a = 0.f, c = 0.f;
#pragma unroll
            for (int j = 0; j < 8; j++) {
                a += w0[j] * rr[bb][j];
                c += w1[j] * rr[bb][j];
            }
            d0[bb] = a; d1[bb] = c;
        }
#pragma unroll
        for (int off = 1; off < 64; off <<= 1) {
#pragma unroll
            for (int bb = 0; bb < BB; bb++) {
                d0[bb] += __shfl_xor(d0[bb], off, 64);
                d1[bb] += __shfl_xor(d1[bb], off, 64);
            }
        }
        if (lane == 0) {
            float vb0 = Wvb[t], vb1 = Wvb[t + 1];
#pragma unroll
            for (int bb = 0; bb < BB; bb++) {
                s_o[bb * DT + t]     = g4[bb] * (d0[bb] + vb0);
                s_o[bb * DT + t + 1] = g4[bb] * (d1[bb] + vb1);
            }
        }
    }
    __syncthreads();
    // s_o flat layout == out0 rows b0..b0+3: one coalesced float2 per thread
    {
        float2 o = ((const float2*)s_o)[tid];
        *(float2*)(out0 + (size_t)b0 * DT + 2 * tid) = o;
    }
}

extern "C" void kernel_launch(void* const* d_in, const int* in_sizes, int n_in,
                              void* d_out, int out_size, void* d_ws, size_t ws_size,
                              hipStream_t stream) {
    const float* Q    = (const float*)d_in[0];
    const float* feat = (const float*)d_in[1];
    const float* Wk   = (const float*)d_in[2];
    // d_in[3] = Wk_b: constant across channels -> cancels in softmax (zeros), unused.
    const float* Wv   = (const float*)d_in[4];
    const float* Wvb  = (const float*)d_in[5];
    const float* g1w  = (const float*)d_in[6];
    const float* g1b  = (const float*)d_in[7];
    const float* g2w  = (const float*)d_in[8];
    const float* g2b  = (const float*)d_in[9];
    float* out0 = (float*)d_out;
    float* out1 = out0 + (size_t)B * DT;
    (void)d_ws; (void)ws_size;  // poison fills are unconditional; scratch unneeded

    hipLaunchKernelGGL(fused_kernel, dim3(B / BB), dim3(1024), 0, stream,
                       Q, feat, Wk, Wv, Wvb, g1w, g1b, g2w, g2b, out0, out1);
}